// Round 1
// baseline (933.292 us; speedup 1.0000x reference)
//
#include <hip/hip_runtime.h>

#define DEVI __device__ __forceinline__

// ---------- helpers ----------
DEVI unsigned fkey(float f) {             // order-preserving float->uint key
  unsigned u = __float_as_uint(f);
  return u ^ ((u >> 31) ? 0xFFFFFFFFu : 0x80000000u);
}
DEVI float funkey(unsigned k) {
  unsigned b = (k & 0x80000000u) ? (k ^ 0x80000000u) : ~k;
  return __uint_as_float(b);
}
DEVI float f4get(const float4& v, int j) {
  return j == 0 ? v.x : j == 1 ? v.y : j == 2 ? v.z : v.w;
}

// ---------- init: zero degree counts + softmax scalars ----------
__global__ void k_init(int* __restrict__ deg, unsigned* __restrict__ scal, int N) {
  int i = blockIdx.x * 256 + threadIdx.x;
  if (i < N) deg[i] = 0;
  if (blockIdx.x == 0 && threadIdx.x == 0) { scal[0] = 0u; scal[1] = 0u; }
}

// ---------- in-degree histogram ----------
__global__ void k_hist(const int* __restrict__ dst, int* __restrict__ deg, int E) {
  int i = blockIdx.x * 256 + threadIdx.x;
  if (i < E) atomicAdd(&deg[dst[i]], 1);
}

// ---------- dinv = rsqrt(deg+1)  (self-loop included) ----------
__global__ void k_dinv(const int* __restrict__ deg, float* __restrict__ dinv, int N) {
  int i = blockIdx.x * 256 + threadIdx.x;
  if (i < N) dinv[i] = rsqrtf((float)(deg[i] + 1));
}

// ---------- 2-level exclusive scan over deg -> rowptr (and cursor copy) ----------
constexpr int SCAN_T = 256, SCAN_V = 8, SCAN_E = SCAN_T * SCAN_V;  // 2048/block

__global__ void k_scan_partial(const int* __restrict__ deg, int* __restrict__ bsum, int N) {
  __shared__ int s[SCAN_T];
  int base = blockIdx.x * SCAN_E + threadIdx.x * SCAN_V;
  int t = 0;
#pragma unroll
  for (int j = 0; j < SCAN_V; j++) { int i = base + j; t += (i < N) ? deg[i] : 0; }
  s[threadIdx.x] = t; __syncthreads();
  for (int o = 128; o > 0; o >>= 1) {
    if (threadIdx.x < o) s[threadIdx.x] += s[threadIdx.x + o];
    __syncthreads();
  }
  if (threadIdx.x == 0) bsum[blockIdx.x] = s[0];
}

__global__ void k_scan_block(const int* __restrict__ bsum, int* __restrict__ boff, int nblk) {
  if (threadIdx.x == 0) {
    int run = 0;
    for (int b = 0; b < nblk; b++) { boff[b] = run; run += bsum[b]; }
  }
}

__global__ void k_scan_write(const int* __restrict__ deg, const int* __restrict__ boff,
                             int* __restrict__ rowptr, int* __restrict__ cursor, int N) {
  __shared__ int s[SCAN_T];
  int tid = threadIdx.x;
  int base = blockIdx.x * SCAN_E + tid * SCAN_V;
  int v[SCAN_V]; int t = 0;
#pragma unroll
  for (int j = 0; j < SCAN_V; j++) { int i = base + j; v[j] = (i < N) ? deg[i] : 0; t += v[j]; }
  s[tid] = t; __syncthreads();
  for (int o = 1; o < SCAN_T; o <<= 1) {   // inclusive Hillis-Steele
    int add = (tid >= o) ? s[tid - o] : 0;
    __syncthreads();
    s[tid] += add;
    __syncthreads();
  }
  int excl = s[tid] - t + boff[blockIdx.x];
#pragma unroll
  for (int j = 0; j < SCAN_V; j++) {
    int i = base + j;
    if (i < N) { rowptr[i] = excl; cursor[i] = excl; }
    excl += v[j];
  }
}

// ---------- scatter edges into CSR slots (order within a node irrelevant) ----------
__global__ void k_scatter(const int* __restrict__ src, const int* __restrict__ dst,
                          int* __restrict__ cursor, int* __restrict__ col, int E) {
  int i = blockIdx.x * 256 + threadIdx.x;
  if (i < E) {
    int d = dst[i];
    int pos = atomicAdd(&cursor[d], 1);
    col[pos] = src[i];
  }
}

// ---------- generic tall-skinny fp32 GEMM: out = post(in[NxK] @ W[KxCOLS]) ----------
// per-thread micro-tile: 4 rows x 8 cols; W staged in LDS; x read straight from global (L1-served)
template <int K, int COLS, bool BIAS, bool RELU, bool SCALE, bool DOMAX>
__launch_bounds__(256)
__global__ void k_gemm(const float* __restrict__ in, const float* __restrict__ W,
                       const float* __restrict__ bias, const float* __restrict__ dinv,
                       float* __restrict__ out, int N, unsigned* __restrict__ gmax) {
  constexpr int CG = COLS / 8;        // col-groups of 8
  constexpr int RG = 256 / CG;        // row-groups of 4 rows
  constexpr int RPB = RG * 4;         // rows per block
  __shared__ float Wl[K * COLS];
  __shared__ float red[256];
  for (int i = threadIdx.x; i < K * COLS; i += 256) Wl[i] = W[i];
  __syncthreads();

  int cg = threadIdx.x % CG, rg = threadIdx.x / CG;
  int c0 = cg * 8;
  long r0 = (long)blockIdx.x * RPB + rg * 4;

  float acc[4][8];
#pragma unroll
  for (int i = 0; i < 4; i++)
#pragma unroll
    for (int c = 0; c < 8; c++) acc[i][c] = 0.f;
  bool rv[4];
#pragma unroll
  for (int i = 0; i < 4; i++) rv[i] = (r0 + i) < (long)N;

  const float* ip = in + r0 * K;
  for (int k = 0; k < K; k += 4) {
    float4 xv[4];
#pragma unroll
    for (int i = 0; i < 4; i++)
      xv[i] = rv[i] ? *(const float4*)(ip + (long)i * K + k) : make_float4(0.f, 0.f, 0.f, 0.f);
#pragma unroll
    for (int jj = 0; jj < 4; jj++) {
      const float4 wa = *(const float4*)&Wl[(k + jj) * COLS + c0];
      const float4 wb = *(const float4*)&Wl[(k + jj) * COLS + c0 + 4];
#pragma unroll
      for (int i = 0; i < 4; i++) {
        float xs = f4get(xv[i], jj);
        acc[i][0] = fmaf(xs, wa.x, acc[i][0]);
        acc[i][1] = fmaf(xs, wa.y, acc[i][1]);
        acc[i][2] = fmaf(xs, wa.z, acc[i][2]);
        acc[i][3] = fmaf(xs, wa.w, acc[i][3]);
        acc[i][4] = fmaf(xs, wb.x, acc[i][4]);
        acc[i][5] = fmaf(xs, wb.y, acc[i][5]);
        acc[i][6] = fmaf(xs, wb.z, acc[i][6]);
        acc[i][7] = fmaf(xs, wb.w, acc[i][7]);
      }
    }
  }

  float bo[8];
  if (BIAS) {
#pragma unroll
    for (int c = 0; c < 8; c++) bo[c] = bias[c0 + c];
  }
  float m = -3.4e38f;
#pragma unroll
  for (int i = 0; i < 4; i++) {
    if (!rv[i]) continue;
    float dv = SCALE ? dinv[r0 + i] : 1.f;
    float o[8];
#pragma unroll
    for (int c = 0; c < 8; c++) {
      float v = acc[i][c];
      if (BIAS) v += bo[c];
      if (SCALE) v *= dv;
      if (RELU) v = fmaxf(v, 0.f);
      if (DOMAX) m = fmaxf(m, v);
      o[c] = v;
    }
    float* op = &out[(r0 + i) * COLS + c0];
    *(float4*)(op) = make_float4(o[0], o[1], o[2], o[3]);
    *(float4*)(op + 4) = make_float4(o[4], o[5], o[6], o[7]);
  }
  if (DOMAX) {
    red[threadIdx.x] = m;
    __syncthreads();
    for (int o = 128; o > 0; o >>= 1) {
      if (threadIdx.x < o) red[threadIdx.x] = fmaxf(red[threadIdx.x], red[threadIdx.x + o]);
      __syncthreads();
    }
    if (threadIdx.x == 0) atomicMax(gmax, fkey(red[0]));
  }
}

// ---------- GCN aggregation: z[v] = relu(b + dinv[v]*(g[v] + sum_{u in in(v)} g[u])) ----------
template <int FEAT>
__launch_bounds__(256)
__global__ void k_agg(const float* __restrict__ g, const int* __restrict__ col,
                      const int* __restrict__ rowptr, const int* __restrict__ deg,
                      const float* __restrict__ dinv, const float* __restrict__ bias,
                      float* __restrict__ z, int N) {
  constexpr int NPB = 256 / FEAT;
  int nib = threadIdx.x / FEAT;
  int c = threadIdx.x % FEAT;
  long v = (long)blockIdx.x * NPB + nib;
  if (v >= N) return;

  float acc = g[v * FEAT + c];  // self-loop term (dinv[v] applied below)
  int start = rowptr[v], dg = deg[v];
  int e = 0;
  while (e < dg) {
    int cnt = min(FEAT, dg - e);
    int idx = (c < cnt) ? col[start + e + c] : 0;
    int j = 0;
    for (; j + 4 <= cnt; j += 4) {  // 4-way MLP: independent gathers per iter
      int u0 = __shfl(idx, j, FEAT);
      int u1 = __shfl(idx, j + 1, FEAT);
      int u2 = __shfl(idx, j + 2, FEAT);
      int u3 = __shfl(idx, j + 3, FEAT);
      float a0 = g[(long)u0 * FEAT + c];
      float a1 = g[(long)u1 * FEAT + c];
      float a2 = g[(long)u2 * FEAT + c];
      float a3 = g[(long)u3 * FEAT + c];
      acc += (a0 + a1) + (a2 + a3);
    }
    for (; j < cnt; j++) {
      int u = __shfl(idx, j, FEAT);
      acc += g[(long)u * FEAT + c];
    }
    e += cnt;
  }
  float o = bias[c] + dinv[v] * acc;
  z[v * FEAT + c] = fmaxf(o, 0.f);
}

// ---------- softmax: sum of exp(l - gmax) ----------
__global__ void k_smsum(const float* __restrict__ logit, unsigned* __restrict__ scal, int total) {
  __shared__ float s[256];
  float gmax = funkey(scal[0]);
  float loc = 0.f;
  for (int i = blockIdx.x * 256 + threadIdx.x; i < total; i += gridDim.x * 256)
    loc += expf(logit[i] - gmax);
  s[threadIdx.x] = loc; __syncthreads();
  for (int o = 128; o > 0; o >>= 1) {
    if (threadIdx.x < o) s[threadIdx.x] += s[threadIdx.x + o];
    __syncthreads();
  }
  if (threadIdx.x == 0) atomicAdd((float*)&scal[1], s[0]);
}

__global__ void k_smnorm(float* __restrict__ logit, const unsigned* __restrict__ scal, int total) {
  float gmax = funkey(scal[0]);
  float inv = 1.0f / __uint_as_float(scal[1]);
  int i = blockIdx.x * 256 + threadIdx.x;
  if (i < total) logit[i] = expf(logit[i] - gmax) * inv;
}

// ---------- launch ----------
extern "C" void kernel_launch(void* const* d_in, const int* in_sizes, int n_in,
                              void* d_out, int out_size, void* d_ws, size_t ws_size,
                              hipStream_t stream) {
  const float* x   = (const float*)d_in[0];
  const int*   ei  = (const int*)d_in[1];
  const float* W1  = (const float*)d_in[3];
  const float* b1  = (const float*)d_in[4];
  const float* W2  = (const float*)d_in[5];
  const float* b2  = (const float*)d_in[6];
  const float* Wo1 = (const float*)d_in[7];
  const float* bo1 = (const float*)d_in[8];
  const float* Wo2 = (const float*)d_in[9];
  const float* bo2 = (const float*)d_in[10];

  const int N = in_sizes[0] / 256;   // in_dim = 256
  const int E = in_sizes[1] / 2;
  const int* src = ei;
  const int* dst = ei + E;

  // workspace carve (aliasing plan: R1 = [g1|z1] then reused whole as z2; R2 = g2 then t)
  size_t o = 0;
  auto carve = [&](size_t bytes) -> char* {
    char* p = (char*)d_ws + o;
    o += (bytes + 255) & ~(size_t)255;
    return p;
  };
  float* R1     = (float*)carve((size_t)N * 64 * 4);  // g1 (N*32), z1 (N*32); later z2 (N*64)
  float* R2     = (float*)carve((size_t)N * 64 * 4);  // g2; later t
  int*   col    = (int*)carve((size_t)E * 4);
  int*   deg    = (int*)carve((size_t)N * 4);
  float* dinv   = (float*)carve((size_t)N * 4);
  int*   rowptr = (int*)carve((size_t)N * 4);
  int*   cursor = (int*)carve((size_t)N * 4);
  const int NBLK = (N + SCAN_E - 1) / SCAN_E;
  int*   bsum   = (int*)carve((size_t)NBLK * 4 + 256);
  int*   boff   = (int*)carve((size_t)NBLK * 4 + 256);
  unsigned* scal = (unsigned*)carve(64);

  float* g1 = R1;
  float* z1 = R1 + (size_t)N * 32;
  float* g2 = R2;
  float* z2 = R1;          // overlays g1/z1 after they are dead
  float* t  = R2;          // overlays g2 after it is dead
  float* logits = (float*)d_out;

  const int gN = (N + 255) / 256;
  const int gE = (E + 255) / 256;

  k_init<<<gN, 256, 0, stream>>>(deg, scal, N);
  k_hist<<<gE, 256, 0, stream>>>(dst, deg, E);
  k_dinv<<<gN, 256, 0, stream>>>(deg, dinv, N);
  k_scan_partial<<<NBLK, 256, 0, stream>>>(deg, bsum, N);
  k_scan_block<<<1, 64, 0, stream>>>(bsum, boff, NBLK);
  k_scan_write<<<NBLK, 256, 0, stream>>>(deg, boff, rowptr, cursor, N);
  k_scatter<<<gE, 256, 0, stream>>>(src, dst, cursor, col, E);

  // layer 1: g1 = dinv .* (x @ W1); z1 = relu(b1 + dinv*(g1[v] + sum g1[u]))
  k_gemm<256, 32, false, false, true, false>
      <<<(N + 255) / 256, 256, 0, stream>>>(x, W1, nullptr, dinv, g1, N, nullptr);
  k_agg<32><<<(N + 7) / 8, 256, 0, stream>>>(g1, col, rowptr, deg, dinv, b1, z1, N);

  // layer 2: g2 = dinv .* (z1 @ W2); z2 = relu(b2 + dinv*(g2[v] + sum g2[u]))
  k_gemm<32, 64, false, false, true, false>
      <<<(N + 127) / 128, 256, 0, stream>>>(z1, W2, nullptr, dinv, g2, N, nullptr);
  k_agg<64><<<(N + 3) / 4, 256, 0, stream>>>(g2, col, rowptr, deg, dinv, b2, z2, N);

  // MLP head: t = relu(z2 @ Wo1 + bo1); logits = t @ Wo2 + bo2 (+ global max)
  k_gemm<64, 64, true, true, false, false>
      <<<(N + 127) / 128, 256, 0, stream>>>(z2, Wo1, bo1, nullptr, t, N, nullptr);
  k_gemm<64, 64, true, false, false, true>
      <<<(N + 127) / 128, 256, 0, stream>>>(t, Wo2, bo2, nullptr, logits, N, scal);

  // softmax over all N*64 logits
  k_smsum<<<1024, 256, 0, stream>>>(logits, scal, out_size);
  k_smnorm<<<(out_size + 255) / 256, 256, 0, stream>>>(logits, scal, out_size);
}

// Round 2
// 635.392 us; speedup vs baseline: 1.4688x; 1.4688x over previous
//
#include <hip/hip_runtime.h>

#define DEVI __device__ __forceinline__

// ---------- helpers ----------
DEVI unsigned fkey(float f) {             // order-preserving float->uint key
  unsigned u = __float_as_uint(f);
  return u ^ ((u >> 31) ? 0xFFFFFFFFu : 0x80000000u);
}
DEVI float funkey(unsigned k) {
  unsigned b = (k & 0x80000000u) ? (k ^ 0x80000000u) : ~k;
  return __uint_as_float(b);
}
DEVI float f4get(const float4& v, int j) {
  return j == 0 ? v.x : j == 1 ? v.y : j == 2 ? v.z : v.w;
}

// ================= CSR build: bucketed counting sort by dst =================
// Buckets of 512 consecutive node ids -> per-bucket edge windows (~64 KB) stay
// L2-resident for the fine scatter; partition writes are per-bucket append
// streams so L2 lines fill completely before eviction.
constexpr int BSH = 9;                 // 512 nodes per bucket
constexpr int BNODES = 1 << BSH;
constexpr int PEPT = 16;               // partition: edges per thread
constexpr int PCHUNK = 256 * PEPT;     // 4096 edges per block

__global__ void k_binit(int* __restrict__ bcnt) {
  bcnt[threadIdx.x] = 0;
}

__global__ void k_bcount(const int* __restrict__ dst, int* __restrict__ bcnt,
                         int E, int NB) {
  __shared__ int lh[256];
  lh[threadIdx.x] = 0;
  __syncthreads();
  int stride = gridDim.x * 256;
  for (long i = (long)blockIdx.x * 256 + threadIdx.x; i < E; i += stride)
    atomicAdd(&lh[dst[i] >> BSH], 1);
  __syncthreads();
  if (threadIdx.x < NB && lh[threadIdx.x]) atomicAdd(&bcnt[threadIdx.x], lh[threadIdx.x]);
}

// exclusive scan over <=256 bucket counts -> bases + cursors; also zero scal
__global__ void k_bscan(const int* __restrict__ bcnt, int* __restrict__ bbase,
                        int* __restrict__ bcur, unsigned* __restrict__ scal, int NB) {
  __shared__ int s[256];
  int t = threadIdx.x;
  int v = (t < NB) ? bcnt[t] : 0;
  s[t] = v;
  __syncthreads();
  for (int o = 1; o < 256; o <<= 1) {
    int add = (t >= o) ? s[t - o] : 0;
    __syncthreads();
    s[t] += add;
    __syncthreads();
  }
  int excl = s[t] - v;
  if (t < NB) { bbase[t] = excl; bcur[t] = excl; }
  if (t == 0) { scal[0] = 0u; scal[1] = 0u; }
}

// partition edges into bucket-ordered packed array; pack = (dst&511)<<17 | src
// (requires N <= 2^17 = 131072; here N = 100000)
__global__ __launch_bounds__(256)
void k_bpart(const int* __restrict__ src, const int* __restrict__ dst,
             int* __restrict__ bcur, unsigned* __restrict__ epart, int E, int NB) {
  __shared__ int lh[256];
  __shared__ int gbase[256];
  long base = (long)blockIdx.x * PCHUNK;
  lh[threadIdx.x] = 0;
  __syncthreads();
  int ed[PEPT]; int es[PEPT]; unsigned short lpos[PEPT];
#pragma unroll
  for (int j = 0; j < PEPT; j++) {
    long i = base + threadIdx.x + (long)j * 256;   // coalesced
    if (i < E) {
      int d = dst[i];
      es[j] = src[i];
      ed[j] = d;
      lpos[j] = (unsigned short)atomicAdd(&lh[d >> BSH], 1);
    } else {
      ed[j] = -1;
    }
  }
  __syncthreads();
  if (threadIdx.x < NB) {
    int c = lh[threadIdx.x];
    gbase[threadIdx.x] = c ? atomicAdd(&bcur[threadIdx.x], c) : 0;
  }
  __syncthreads();
#pragma unroll
  for (int j = 0; j < PEPT; j++) {
    int d = ed[j];
    if (d >= 0) {
      unsigned p = (unsigned)(gbase[d >> BSH] + (int)lpos[j]);
      epart[p] = ((unsigned)(d & (BNODES - 1)) << 17) | (unsigned)es[j];
    }
  }
}

// one block per bucket: per-node degree hist, 512-entry scan -> deg/rowptr/dinv,
// then scatter col (src ids) into the bucket's L2-resident window.
__global__ __launch_bounds__(256)
void k_fine(const unsigned* __restrict__ epart, const int* __restrict__ bbase,
            const int* __restrict__ bcnt, int* __restrict__ rowptr,
            int* __restrict__ deg, float* __restrict__ dinv,
            int* __restrict__ col, int N) {
  __shared__ int lh[BNODES];
  __shared__ int lexcl[BNODES];
  __shared__ int ssc[256];
  int b = blockIdx.x;
  int base = bbase[b], cnt = bcnt[b];
  int nlo = b << BSH;
  int t = threadIdx.x;
  lh[t] = 0; lh[t + 256] = 0;
  __syncthreads();
  for (int i = t; i < cnt; i += 256) {
    unsigned e = epart[base + i];
    atomicAdd(&lh[e >> 17], 1);
  }
  __syncthreads();
  int a0 = lh[2 * t], a1 = lh[2 * t + 1];
  ssc[t] = a0 + a1;
  __syncthreads();
  for (int o = 1; o < 256; o <<= 1) {
    int add = (t >= o) ? ssc[t - o] : 0;
    __syncthreads();
    ssc[t] += add;
    __syncthreads();
  }
  int excl = ssc[t] - (a0 + a1);
  lexcl[2 * t] = excl;
  lexcl[2 * t + 1] = excl + a0;
  __syncthreads();
#pragma unroll
  for (int k = 0; k < 2; k++) {
    int i = t + k * 256;
    int v = nlo + i;
    if (v < N) {
      int dgv = lh[i];
      deg[v] = dgv;
      rowptr[v] = base + lexcl[i];
      dinv[v] = rsqrtf((float)(dgv + 1));
    }
  }
  __syncthreads();
  lh[2 * t] = lexcl[2 * t];
  lh[2 * t + 1] = lexcl[2 * t + 1];
  __syncthreads();
  for (int i = t; i < cnt; i += 256) {
    unsigned e = epart[base + i];
    int p = atomicAdd(&lh[e >> 17], 1);
    col[base + p] = (int)(e & 0x1FFFFu);
  }
}

// ---------- generic tall-skinny fp32 GEMM: out = post(in[NxK] @ W[KxCOLS]) ----------
template <int K, int COLS, bool BIAS, bool RELU, bool SCALE, bool DOMAX>
__launch_bounds__(256)
__global__ void k_gemm(const float* __restrict__ in, const float* __restrict__ W,
                       const float* __restrict__ bias, const float* __restrict__ dinv,
                       float* __restrict__ out, int N, unsigned* __restrict__ gmax) {
  constexpr int CG = COLS / 8;        // col-groups of 8
  constexpr int RG = 256 / CG;        // row-groups of 4 rows
  constexpr int RPB = RG * 4;         // rows per block
  __shared__ float Wl[K * COLS];
  __shared__ float red[256];
  for (int i = threadIdx.x; i < K * COLS; i += 256) Wl[i] = W[i];
  __syncthreads();

  int cg = threadIdx.x % CG, rg = threadIdx.x / CG;
  int c0 = cg * 8;
  long r0 = (long)blockIdx.x * RPB + rg * 4;

  float acc[4][8];
#pragma unroll
  for (int i = 0; i < 4; i++)
#pragma unroll
    for (int c = 0; c < 8; c++) acc[i][c] = 0.f;
  bool rv[4];
#pragma unroll
  for (int i = 0; i < 4; i++) rv[i] = (r0 + i) < (long)N;

  const float* ip = in + r0 * K;
  for (int k = 0; k < K; k += 4) {
    float4 xv[4];
#pragma unroll
    for (int i = 0; i < 4; i++)
      xv[i] = rv[i] ? *(const float4*)(ip + (long)i * K + k) : make_float4(0.f, 0.f, 0.f, 0.f);
#pragma unroll
    for (int jj = 0; jj < 4; jj++) {
      const float4 wa = *(const float4*)&Wl[(k + jj) * COLS + c0];
      const float4 wb = *(const float4*)&Wl[(k + jj) * COLS + c0 + 4];
#pragma unroll
      for (int i = 0; i < 4; i++) {
        float xs = f4get(xv[i], jj);
        acc[i][0] = fmaf(xs, wa.x, acc[i][0]);
        acc[i][1] = fmaf(xs, wa.y, acc[i][1]);
        acc[i][2] = fmaf(xs, wa.z, acc[i][2]);
        acc[i][3] = fmaf(xs, wa.w, acc[i][3]);
        acc[i][4] = fmaf(xs, wb.x, acc[i][4]);
        acc[i][5] = fmaf(xs, wb.y, acc[i][5]);
        acc[i][6] = fmaf(xs, wb.z, acc[i][6]);
        acc[i][7] = fmaf(xs, wb.w, acc[i][7]);
      }
    }
  }

  float bo[8];
  if (BIAS) {
#pragma unroll
    for (int c = 0; c < 8; c++) bo[c] = bias[c0 + c];
  }
  float m = -3.4e38f;
#pragma unroll
  for (int i = 0; i < 4; i++) {
    if (!rv[i]) continue;
    float dv = SCALE ? dinv[r0 + i] : 1.f;
    float o[8];
#pragma unroll
    for (int c = 0; c < 8; c++) {
      float v = acc[i][c];
      if (BIAS) v += bo[c];
      if (SCALE) v *= dv;
      if (RELU) v = fmaxf(v, 0.f);
      if (DOMAX) m = fmaxf(m, v);
      o[c] = v;
    }
    float* op = &out[(r0 + i) * COLS + c0];
    *(float4*)(op) = make_float4(o[0], o[1], o[2], o[3]);
    *(float4*)(op + 4) = make_float4(o[4], o[5], o[6], o[7]);
  }
  if (DOMAX) {
    red[threadIdx.x] = m;
    __syncthreads();
    for (int o = 128; o > 0; o >>= 1) {
      if (threadIdx.x < o) red[threadIdx.x] = fmaxf(red[threadIdx.x], red[threadIdx.x + o]);
      __syncthreads();
    }
    if (threadIdx.x == 0) atomicMax(gmax, fkey(red[0]));
  }
}

// ---------- GCN aggregation: z[v] = relu(b + dinv[v]*(g[v] + sum_{u in in(v)} g[u])) ----------
template <int FEAT>
__launch_bounds__(256)
__global__ void k_agg(const float* __restrict__ g, const int* __restrict__ col,
                      const int* __restrict__ rowptr, const int* __restrict__ deg,
                      const float* __restrict__ dinv, const float* __restrict__ bias,
                      float* __restrict__ z, int N) {
  constexpr int NPB = 256 / FEAT;
  int nib = threadIdx.x / FEAT;
  int c = threadIdx.x % FEAT;
  long v = (long)blockIdx.x * NPB + nib;
  if (v >= N) return;

  float acc = g[v * FEAT + c];  // self-loop term (dinv[v] applied below)
  int start = rowptr[v], dg = deg[v];
  int e = 0;
  while (e < dg) {
    int cnt = min(FEAT, dg - e);
    int idx = (c < cnt) ? col[start + e + c] : 0;
    int j = 0;
    for (; j + 4 <= cnt; j += 4) {  // 4-way MLP: independent gathers per iter
      int u0 = __shfl(idx, j, FEAT);
      int u1 = __shfl(idx, j + 1, FEAT);
      int u2 = __shfl(idx, j + 2, FEAT);
      int u3 = __shfl(idx, j + 3, FEAT);
      float a0 = g[(long)u0 * FEAT + c];
      float a1 = g[(long)u1 * FEAT + c];
      float a2 = g[(long)u2 * FEAT + c];
      float a3 = g[(long)u3 * FEAT + c];
      acc += (a0 + a1) + (a2 + a3);
    }
    for (; j < cnt; j++) {
      int u = __shfl(idx, j, FEAT);
      acc += g[(long)u * FEAT + c];
    }
    e += cnt;
  }
  float o = bias[c] + dinv[v] * acc;
  z[v * FEAT + c] = fmaxf(o, 0.f);
}

// ---------- softmax: sum of exp(l - gmax) ----------
__global__ void k_smsum(const float* __restrict__ logit, unsigned* __restrict__ scal, int total) {
  __shared__ float s[256];
  float gmax = funkey(scal[0]);
  float loc = 0.f;
  for (int i = blockIdx.x * 256 + threadIdx.x; i < total; i += gridDim.x * 256)
    loc += expf(logit[i] - gmax);
  s[threadIdx.x] = loc; __syncthreads();
  for (int o = 128; o > 0; o >>= 1) {
    if (threadIdx.x < o) s[threadIdx.x] += s[threadIdx.x + o];
    __syncthreads();
  }
  if (threadIdx.x == 0) atomicAdd((float*)&scal[1], s[0]);
}

__global__ void k_smnorm(float* __restrict__ logit, const unsigned* __restrict__ scal, int total) {
  float gmax = funkey(scal[0]);
  float inv = 1.0f / __uint_as_float(scal[1]);
  int i = blockIdx.x * 256 + threadIdx.x;
  if (i < total) logit[i] = expf(logit[i] - gmax) * inv;
}

// ---------- launch ----------
extern "C" void kernel_launch(void* const* d_in, const int* in_sizes, int n_in,
                              void* d_out, int out_size, void* d_ws, size_t ws_size,
                              hipStream_t stream) {
  const float* x   = (const float*)d_in[0];
  const int*   ei  = (const int*)d_in[1];
  const float* W1  = (const float*)d_in[3];
  const float* b1  = (const float*)d_in[4];
  const float* W2  = (const float*)d_in[5];
  const float* b2  = (const float*)d_in[6];
  const float* Wo1 = (const float*)d_in[7];
  const float* bo1 = (const float*)d_in[8];
  const float* Wo2 = (const float*)d_in[9];
  const float* bo2 = (const float*)d_in[10];

  const int N = in_sizes[0] / 256;   // in_dim = 256
  const int E = in_sizes[1] / 2;
  const int* src = ei;
  const int* dst = ei + E;
  const int NB = (N + BNODES - 1) / BNODES;   // 196 buckets (<=256 required)

  // workspace carve
  size_t o = 0;
  auto carve = [&](size_t bytes) -> char* {
    char* p = (char*)d_ws + o;
    o += (bytes + 255) & ~(size_t)255;
    return p;
  };
  float* R1     = (float*)carve((size_t)N * 64 * 4);  // g1 (N*32) | z1 (N*32); later z2 (N*64)
  float* R2     = (float*)carve((size_t)N * 64 * 4);  // epart during CSR build; g2; later t
  int*   col    = (int*)carve((size_t)E * 4);
  int*   deg    = (int*)carve((size_t)N * 4);
  float* dinv   = (float*)carve((size_t)N * 4);
  int*   rowptr = (int*)carve((size_t)N * 4);
  int*   bcnt   = (int*)carve(256 * 4);
  int*   bbase  = (int*)carve(256 * 4);
  int*   bcur   = (int*)carve(256 * 4);
  unsigned* scal = (unsigned*)carve(64);

  float* g1 = R1;
  float* z1 = R1 + (size_t)N * 32;
  float* g2 = R2;
  float* z2 = R1;          // overlays g1/z1 after they are dead
  float* t  = R2;          // overlays g2 after it is dead
  unsigned* epart = (unsigned*)R2;  // CSR build scratch, dead before g2 is written
  float* logits = (float*)d_out;

  // ---- CSR build (bucketed counting sort) ----
  k_binit<<<1, 256, 0, stream>>>(bcnt);
  k_bcount<<<512, 256, 0, stream>>>(dst, bcnt, E, NB);
  k_bscan<<<1, 256, 0, stream>>>(bcnt, bbase, bcur, scal, NB);
  k_bpart<<<(E + PCHUNK - 1) / PCHUNK, 256, 0, stream>>>(src, dst, bcur, epart, E, NB);
  k_fine<<<NB, 256, 0, stream>>>(epart, bbase, bcnt, rowptr, deg, dinv, col, N);

  // layer 1: g1 = dinv .* (x @ W1); z1 = relu(b1 + dinv*(g1[v] + sum g1[u]))
  k_gemm<256, 32, false, false, true, false>
      <<<(N + 255) / 256, 256, 0, stream>>>(x, W1, nullptr, dinv, g1, N, nullptr);
  k_agg<32><<<(N + 7) / 8, 256, 0, stream>>>(g1, col, rowptr, deg, dinv, b1, z1, N);

  // layer 2: g2 = dinv .* (z1 @ W2); z2 = relu(b2 + dinv*(g2[v] + sum g2[u]))
  k_gemm<32, 64, false, false, true, false>
      <<<(N + 127) / 128, 256, 0, stream>>>(z1, W2, nullptr, dinv, g2, N, nullptr);
  k_agg<64><<<(N + 3) / 4, 256, 0, stream>>>(g2, col, rowptr, deg, dinv, b2, z2, N);

  // MLP head: t = relu(z2 @ Wo1 + bo1); logits = t @ Wo2 + bo2 (+ global max)
  k_gemm<64, 64, true, true, false, false>
      <<<(N + 127) / 128, 256, 0, stream>>>(z2, Wo1, bo1, nullptr, t, N, nullptr);
  k_gemm<64, 64, true, false, false, true>
      <<<(N + 127) / 128, 256, 0, stream>>>(t, Wo2, bo2, nullptr, logits, N, scal);

  // softmax over all N*64 logits
  k_smsum<<<1024, 256, 0, stream>>>(logits, scal, out_size);
  k_smnorm<<<(out_size + 255) / 256, 256, 0, stream>>>(logits, scal, out_size);
}